// Round 2
// baseline (2071.462 us; speedup 1.0000x reference)
//
#include <hip/hip_runtime.h>
#include <math.h>

#define NSTEPS 500
#define BATCH  1024
#define DX     32
#define DW     32
#define HDIM   128
#define BETA   0.5f
#define EPSG   1e-4f

typedef short bf8_t __attribute__((ext_vector_type(8)));
typedef float f4_t  __attribute__((ext_vector_type(4)));

union U8 { bf8_t v; unsigned u[4]; };

__device__ __forceinline__ f4_t MFMA(bf8_t a, bf8_t b, f4_t c) {
    return __builtin_amdgcn_mfma_f32_16x16x32_bf16(a, b, c, 0, 0, 0);
}

__device__ __forceinline__ unsigned short f2bf(float x) {   // RNE f32->bf16
    unsigned u = __float_as_uint(x);
    u += 0x7fffu + ((u >> 16) & 1u);
    return (unsigned short)(u >> 16);
}
__device__ __forceinline__ float bf2f(unsigned short h) {
    return __uint_as_float(((unsigned)h) << 16);
}
// pack two f32 -> two bf16 in one u32 (lo = a, hi = b), RNE
__device__ __forceinline__ unsigned cvtpk(float a, float b) {
    unsigned r;
    asm("v_cvt_pk_bf16_f32 %0, %1, %2" : "=v"(r) : "v"(a), "v"(b));
    return r;
}
__device__ __forceinline__ float unplo(unsigned u) { return __uint_as_float(u << 16); }
__device__ __forceinline__ float unphi(unsigned u) { return __uint_as_float(u & 0xffff0000u); }

__device__ __forceinline__ float tanh_fast(float x) {
    float xc = fminf(fmaxf(x, -15.f), 15.f);
    float e  = __expf(2.f * xc);
    return (e - 1.f) / (e + 1.f);
}

// ============================================================================
// Barrier-free design: ONE wave owns 16 batch rows end-to-end.  Everything is
// computed transposed (batch = MFMA column = lane&15), so the MFMA D-layout
// (row = quad*4+i = feature, col = m16 = batch) IS the layout the next layer's
// B-fragment needs, up to a slot->k permutation sigma(q,j) = (j<4 ? 4q+j :
// 16+4q+j-4) which is pre-applied to all resident weight A-fragments (MFMA is
// invariant to consistent k-slot permutation of A and B).  Layer-to-layer
// handoff = 16 v_cvt_pk_bf16_f32, zero LDS, zero barriers, zero shuffles
// (except the 2-op Gval quad-reduce).  Weights live in ~310 VGPRs.
// grid = 64 blocks x 64 threads (1 wave/CU).
// ============================================================================
__global__ __launch_bounds__(64, 1)
void sde_kernel(const float* __restrict__ x0, const float* __restrict__ ts,
                const float* __restrict__ dWs,
                const float* __restrict__ W1, const float* __restrict__ b1,
                const float* __restrict__ W2, const float* __restrict__ b2,
                const float* __restrict__ W3, const float* __restrict__ b3,
                const float* __restrict__ G,  const float* __restrict__ mu,
                const float* __restrict__ vt, float* __restrict__ out)
{
    __shared__ float sts[NSTEPS + 1];
    __shared__ __align__(16) float sG[DX * DW];

    const int lane = threadIdx.x;       // blockDim = 64 (one wave)
    const int m16  = lane & 15;         // batch column of this lane
    const int quad = lane >> 4;
    const int r0   = blockIdx.x * 16;
    const int brow = r0 + m16;

    for (int i = lane; i <= NSTEPS; i += 64) sts[i] = ts[i];
    for (int i = lane; i < DX * DW; i += 64) sG[i] = G[i];
    __syncthreads();

    // slot j -> logical index within a 32-feature block
    int fo[8];
    #pragma unroll
    for (int j = 0; j < 8; ++j) fo[j] = (j < 4) ? (4 * quad + j) : (16 + 4 * quad + (j - 4));

    // ---- resident weight A-fragments (rows = out-features, k pre-permuted) ----
    bf8_t w1T[8];                        // W1^T (x part, K=32)
    #pragma unroll
    for (int mt = 0; mt < 8; ++mt)
        #pragma unroll
        for (int j = 0; j < 8; ++j)
            w1T[mt][j] = (short)f2bf(W1[(1 + fo[j]) * HDIM + mt * 16 + m16]);

    bf8_t w2T[8][4];                     // W2^T (K=128: 4 k-tiles)
    #pragma unroll
    for (int mt = 0; mt < 8; ++mt)
        #pragma unroll
        for (int kt = 0; kt < 4; ++kt)
            #pragma unroll
            for (int j = 0; j < 8; ++j)
                w2T[mt][kt][j] = (short)f2bf(W2[(kt * 32 + fo[j]) * HDIM + mt * 16 + m16]);

    bf8_t w3T[2][4];                     // W3^T (out=32: 2 m-tiles)
    #pragma unroll
    for (int mt = 0; mt < 2; ++mt)
        #pragma unroll
        for (int kt = 0; kt < 4; ++kt)
            #pragma unroll
            for (int j = 0; j < 8; ++j)
                w3T[mt][kt][j] = (short)f2bf(W3[(kt * 32 + fo[j]) * DW + mt * 16 + m16]);

    // per-feature vectors in D-layout (feature = mt*16 + 4*quad + i), bf16-packed
    unsigned w10p[16], b1p[16], b2p[16];
    #pragma unroll
    for (int mt = 0; mt < 8; ++mt) {
        int f0 = mt * 16 + 4 * quad;
        w10p[2 * mt]     = ((unsigned)f2bf(W1[f0 + 1]) << 16) | f2bf(W1[f0]);
        w10p[2 * mt + 1] = ((unsigned)f2bf(W1[f0 + 3]) << 16) | f2bf(W1[f0 + 2]);
        b1p[2 * mt]      = ((unsigned)f2bf(b1[f0 + 1]) << 16) | f2bf(b1[f0]);
        b1p[2 * mt + 1]  = ((unsigned)f2bf(b1[f0 + 3]) << 16) | f2bf(b1[f0 + 2]);
        b2p[2 * mt]      = ((unsigned)f2bf(b2[f0 + 1]) << 16) | f2bf(b2[f0]);
        b2p[2 * mt + 1]  = ((unsigned)f2bf(b2[f0 + 3]) << 16) | f2bf(b2[f0 + 2]);
    }
    float b3r[2][4], mur[2][4], vtr[2][4];
    #pragma unroll
    for (int mt = 0; mt < 2; ++mt)
        #pragma unroll
        for (int i = 0; i < 4; ++i) {
            int f = mt * 16 + 4 * quad + i;
            b3r[mt][i] = b3[f];
            mur[mt][i] = mu[f];
            vtr[mt][i] = vt[f];
        }

    // a = G G^T and G fragments (hi/lo split), A[row=m16 in tile mt][k=fo[j]]
    bf8_t ahi[2], alo[2], ghi[2], glo[2];
    #pragma unroll
    for (int mt = 0; mt < 2; ++mt) {
        float gb[32];
        const f4_t* pb = (const f4_t*)(sG + (mt * 16 + m16) * DW);
        #pragma unroll
        for (int k4 = 0; k4 < 8; ++k4) {
            f4_t t = pb[k4];
            gb[4 * k4] = t[0]; gb[4 * k4 + 1] = t[1]; gb[4 * k4 + 2] = t[2]; gb[4 * k4 + 3] = t[3];
        }
        #pragma unroll
        for (int j = 0; j < 8; ++j) {
            const f4_t* pa = (const f4_t*)(sG + fo[j] * DW);
            float acc = 0.f;
            #pragma unroll
            for (int k4 = 0; k4 < 8; ++k4) {
                f4_t t = pa[k4];
                acc += t[0] * gb[4 * k4] + t[1] * gb[4 * k4 + 1]
                     + t[2] * gb[4 * k4 + 2] + t[3] * gb[4 * k4 + 3];
            }
            unsigned short h = f2bf(acc);
            ahi[mt][j] = (short)h;
            alo[mt][j] = (short)f2bf(acc - bf2f(h));
            float gv = sG[(mt * 16 + m16) * DW + fo[j]];
            unsigned short hg = f2bf(gv);
            ghi[mt][j] = (short)hg;
            glo[mt][j] = (short)f2bf(gv - bf2f(hg));
        }
    }

    // ---- state ----
    float xr[2][4];
    {
        const f4_t* p = (const f4_t*)(x0 + (size_t)brow * DX);
        f4_t a = p[quad], b = p[4 + quad];
        #pragma unroll
        for (int i = 0; i < 4; ++i) { xr[0][i] = a[i]; xr[1][i] = b[i]; }
    }
    f4_t cw0, cw1;    // dW for current step (dx = 4q+i / 16+4q+i)
    {
        const f4_t* p = (const f4_t*)(dWs + (size_t)brow * DW);
        cw0 = p[quad]; cw1 = p[4 + quad];
    }

    const float T = sts[NSTEPS];
    float tcur = sts[0];
    float llr = 0.f;

    float* xs_out = out;
    float* vs_out = out + (size_t)NSTEPS * BATCH * DX;
    float* ll_out = out + (size_t)2 * NSTEPS * BATCH * DX;

    #pragma unroll 1
    for (int s = 0; s < NSTEPS; ++s) {
        const float dt     = sts[s + 1] - sts[s];
        const float sqdt   = sqrtf(dt);
        const float invrem = 1.f / (T - tcur + EPSG);

        // prefetch next step's dW (floats across the whole step body)
        f4_t nw0, nw1;
        {
            int sn = (s + 1 < NSTEPS) ? s + 1 : s;
            const f4_t* p = (const f4_t*)(dWs + (size_t)sn * (BATCH * DW) + (size_t)brow * DW);
            nw0 = p[quad]; nw1 = p[4 + quad];
        }

        // ---- r = (vt - x) * invrem, and its hi/lo B-fragment ----
        float r_[2][4];
        U8 rh, rl;
        #pragma unroll
        for (int mt = 0; mt < 2; ++mt) {
            #pragma unroll
            for (int i = 0; i < 4; ++i) r_[mt][i] = (vtr[mt][i] - xr[mt][i]) * invrem;
            unsigned short h0 = f2bf(r_[mt][0]), h1 = f2bf(r_[mt][1]);
            unsigned short h2 = f2bf(r_[mt][2]), h3 = f2bf(r_[mt][3]);
            rh.u[2 * mt]     = ((unsigned)h1 << 16) | h0;
            rh.u[2 * mt + 1] = ((unsigned)h3 << 16) | h2;
            rl.u[2 * mt]     = cvtpk(r_[mt][0] - bf2f(h0), r_[mt][1] - bf2f(h1));
            rl.u[2 * mt + 1] = cvtpk(r_[mt][2] - bf2f(h2), r_[mt][3] - bf2f(h3));
        }

        // ---- ra = (r@a)^T = a @ r^T (hi/lo, 3 MFMAs per m-tile) ----
        f4_t ra0 = {0, 0, 0, 0}, ra1 = {0, 0, 0, 0};
        ra0 = MFMA(ahi[0], rh.v, ra0);
        ra0 = MFMA(ahi[0], rl.v, ra0);
        ra0 = MFMA(alo[0], rh.v, ra0);
        ra1 = MFMA(ahi[1], rh.v, ra1);
        ra1 = MFMA(ahi[1], rl.v, ra1);
        ra1 = MFMA(alo[1], rh.v, ra1);

        // ---- L1: z1^T = W1^T x^T + (b1 + t*W1row0) ----
        U8 xb;
        xb.u[0] = cvtpk(xr[0][0], xr[0][1]); xb.u[1] = cvtpk(xr[0][2], xr[0][3]);
        xb.u[2] = cvtpk(xr[1][0], xr[1][1]); xb.u[3] = cvtpk(xr[1][2], xr[1][3]);

        U8 bh[4];   // packed h1 B-fragments (kt covers feature m-blocks {2kt,2kt+1})
        #pragma unroll
        for (int mt = 0; mt < 8; ++mt) {
            unsigned ba = b1p[2 * mt], bb = b1p[2 * mt + 1];
            unsigned wa = w10p[2 * mt], wb = w10p[2 * mt + 1];
            f4_t acc;
            acc[0] = unplo(ba) + tcur * unplo(wa);
            acc[1] = unphi(ba) + tcur * unphi(wa);
            acc[2] = unplo(bb) + tcur * unplo(wb);
            acc[3] = unphi(bb) + tcur * unphi(wb);
            acc = MFMA(w1T[mt], xb.v, acc);
            bh[mt >> 1].u[(2 * mt) & 3]     = cvtpk(tanh_fast(acc[0]), tanh_fast(acc[1]));
            bh[mt >> 1].u[(2 * mt + 1) & 3] = cvtpk(tanh_fast(acc[2]), tanh_fast(acc[3]));
        }

        // ---- L2 ----
        U8 bh2[4];
        #pragma unroll
        for (int mt = 0; mt < 8; ++mt) {
            unsigned ba = b2p[2 * mt], bb = b2p[2 * mt + 1];
            f4_t acc;
            acc[0] = unplo(ba); acc[1] = unphi(ba); acc[2] = unplo(bb); acc[3] = unphi(bb);
            #pragma unroll
            for (int kt = 0; kt < 4; ++kt) acc = MFMA(w2T[mt][kt], bh[kt].v, acc);
            bh2[mt >> 1].u[(2 * mt) & 3]     = cvtpk(tanh_fast(acc[0]), tanh_fast(acc[1]));
            bh2[mt >> 1].u[(2 * mt + 1) & 3] = cvtpk(tanh_fast(acc[2]), tanh_fast(acc[3]));
        }

        // ---- L3: v^T = W3^T h2^T + b3 ----
        f4_t v0a = {b3r[0][0], b3r[0][1], b3r[0][2], b3r[0][3]};
        f4_t v1a = {b3r[1][0], b3r[1][1], b3r[1][2], b3r[1][3]};
        #pragma unroll
        for (int kt = 0; kt < 4; ++kt) {
            v0a = MFMA(w3T[0][kt], bh2[kt].v, v0a);
            v1a = MFMA(w3T[1][kt], bh2[kt].v, v1a);
        }

        // ---- u = v*dt + dW*sqrt(dt), hi/lo frag; xg = G @ u^T ----
        float u_[2][4];
        #pragma unroll
        for (int i = 0; i < 4; ++i) {
            u_[0][i] = v0a[i] * dt + cw0[i] * sqdt;
            u_[1][i] = v1a[i] * dt + cw1[i] * sqdt;
        }
        U8 uh, ul;
        #pragma unroll
        for (int mt = 0; mt < 2; ++mt) {
            unsigned short h0 = f2bf(u_[mt][0]), h1 = f2bf(u_[mt][1]);
            unsigned short h2 = f2bf(u_[mt][2]), h3 = f2bf(u_[mt][3]);
            uh.u[2 * mt]     = ((unsigned)h1 << 16) | h0;
            uh.u[2 * mt + 1] = ((unsigned)h3 << 16) | h2;
            ul.u[2 * mt]     = cvtpk(u_[mt][0] - bf2f(h0), u_[mt][1] - bf2f(h1));
            ul.u[2 * mt + 1] = cvtpk(u_[mt][2] - bf2f(h2), u_[mt][3] - bf2f(h3));
        }
        f4_t xg0 = {0, 0, 0, 0}, xg1 = {0, 0, 0, 0};
        xg0 = MFMA(ghi[0], uh.v, xg0);
        xg0 = MFMA(ghi[0], ul.v, xg0);
        xg0 = MFMA(glo[0], uh.v, xg0);
        xg1 = MFMA(ghi[1], uh.v, xg1);
        xg1 = MFMA(ghi[1], ul.v, xg1);
        xg1 = MFMA(glo[1], uh.v, xg1);

        // ---- Gval: per-lane partial over its 8 dx, then quad-reduce ----
        float gs = 0.f;
        #pragma unroll
        for (int i = 0; i < 4; ++i) {
            float fb0 = BETA * (mur[0][i] - xr[0][i]);
            float fb1 = BETA * (mur[1][i] - xr[1][i]);
            gs += fb0 * r_[0][i] - 0.5f * r_[0][i] * ra0[i];
            gs += fb1 * r_[1][i] - 0.5f * r_[1][i] * ra1[i];
        }
        gs += __shfl_xor(gs, 16, 64);
        gs += __shfl_xor(gs, 32, 64);
        llr += gs * dt;

        // ---- x update + stores ----
        f4_t xo0, xo1;
        #pragma unroll
        for (int i = 0; i < 4; ++i) {
            float fb0 = BETA * (mur[0][i] - xr[0][i]);
            float fb1 = BETA * (mur[1][i] - xr[1][i]);
            float xn0 = xr[0][i] + (fb0 + ra0[i]) * dt + xg0[i];
            float xn1 = xr[1][i] + (fb1 + ra1[i]) * dt + xg1[i];
            xr[0][i] = xn0; xr[1][i] = xn1;
            xo0[i] = xn0; xo1[i] = xn1;
        }
        {
            f4_t* px = (f4_t*)(xs_out + (size_t)s * (BATCH * DX) + (size_t)brow * DX);
            px[quad]     = xo0;
            px[4 + quad] = xo1;
            f4_t* pv = (f4_t*)(vs_out + (size_t)s * (BATCH * DX) + (size_t)brow * DX);
            pv[quad]     = v0a;
            pv[4 + quad] = v1a;
        }

        cw0 = nw0; cw1 = nw1;
        tcur += dt;
    }

    if (quad == 0) ll_out[brow] = llr;
}

extern "C" void kernel_launch(void* const* d_in, const int* in_sizes, int n_in,
                              void* d_out, int out_size, void* d_ws, size_t ws_size,
                              hipStream_t stream) {
    const float* x0 = (const float*)d_in[0];
    const float* ts = (const float*)d_in[1];
    const float* dWs = (const float*)d_in[2];
    const float* W1 = (const float*)d_in[3];
    const float* b1 = (const float*)d_in[4];
    const float* W2 = (const float*)d_in[5];
    const float* b2 = (const float*)d_in[6];
    const float* W3 = (const float*)d_in[7];
    const float* b3 = (const float*)d_in[8];
    const float* G  = (const float*)d_in[9];
    const float* mu = (const float*)d_in[10];
    const float* vt = (const float*)d_in[11];
    hipLaunchKernelGGL(sde_kernel, dim3(BATCH / 16), dim3(64), 0, stream,
                       x0, ts, dWs, W1, b1, W2, b2, W3, b3, G, mu, vt, (float*)d_out);
}

// Round 3
// 1339.800 us; speedup vs baseline: 1.5461x; 1.5461x over previous
//
#include <hip/hip_runtime.h>
#include <math.h>

#define NSTEPS 500
#define BATCH  1024
#define DX     32
#define DW     32
#define HDIM   128
#define BETA   0.5f
#define EPSG   1e-4f
#define SC     2.8853900817779268f   // 2*log2(e): pre-scale for exp2-based tanh

typedef short bf8_t __attribute__((ext_vector_type(8)));
typedef float f4_t  __attribute__((ext_vector_type(4)));

union U8 { bf8_t v; unsigned u[4]; };

__device__ __forceinline__ f4_t MFMA(bf8_t a, bf8_t b, f4_t c) {
    return __builtin_amdgcn_mfma_f32_16x16x32_bf16(a, b, c, 0, 0, 0);
}

__device__ __forceinline__ unsigned short f2bf(float x) {   // RNE f32->bf16 (host-side style, preamble only)
    unsigned u = __float_as_uint(x);
    u += 0x7fffu + ((u >> 16) & 1u);
    return (unsigned short)(u >> 16);
}
__device__ __forceinline__ float bf2f(unsigned short h) {
    return __uint_as_float(((unsigned)h) << 16);
}
// pack two f32 -> two bf16 in one u32 (lo = a, hi = b), RNE
__device__ __forceinline__ unsigned cvtpk(float a, float b) {
    unsigned r;
    asm("v_cvt_pk_bf16_f32 %0, %1, %2" : "=v"(r) : "v"(a), "v"(b));
    return r;
}
__device__ __forceinline__ float unplo(unsigned u) { return __uint_as_float(u << 16); }
__device__ __forceinline__ float unphi(unsigned u) { return __uint_as_float(u & 0xffff0000u); }

__device__ __forceinline__ float exp2_hw(float x) {
    float r; asm("v_exp_f32 %0, %1" : "=v"(r) : "v"(x)); return r;
}
__device__ __forceinline__ float rcp_hw(float x) {
    float r; asm("v_rcp_f32 %0, %1" : "=v"(r) : "v"(x)); return r;
}
// tanh(z) given zs = 2*log2(e)*z (scale pre-folded into weights/biases).
// 1 - 2/(2^zs + 1): saturates correctly at +-1 for large |zs| (inf/0 safe).
__device__ __forceinline__ float tanh_s(float zs) {
    return fmaf(-2.f, rcp_hw(exp2_hw(zs) + 1.f), 1.f);
}

// hi/lo bf16 split of a pair via cvtpk (6 instr per 2 values)
__device__ __forceinline__ void hilo_pk(float a, float b, unsigned& hp, unsigned& lp) {
    hp = cvtpk(a, b);
    lp = cvtpk(a - unplo(hp), b - unphi(hp));
}

// ============================================================================
// Barrier-free: ONE wave owns 16 batch rows end-to-end, all transposed
// (batch = MFMA col = lane&15).  D-layout == next B-fragment layout under the
// k-slot permutation sigma(q,j) pre-applied to all weight A-fragments.
// Handoff between layers = v_cvt_pk_bf16_f32 only.  Weights resident in VGPRs.
// This round: exp2-prescaled tanh (no div/clamp), cvtpk hi/lo packing,
// f32-resident L1 C-init (incremental), dW-half of the diffusion term hoisted
// off the critical tail, no per-step shuffles.
// ============================================================================
__global__ __launch_bounds__(64, 1)
void sde_kernel(const float* __restrict__ x0, const float* __restrict__ ts,
                const float* __restrict__ dWs,
                const float* __restrict__ W1, const float* __restrict__ b1,
                const float* __restrict__ W2, const float* __restrict__ b2,
                const float* __restrict__ W3, const float* __restrict__ b3,
                const float* __restrict__ G,  const float* __restrict__ mu,
                const float* __restrict__ vt, float* __restrict__ out)
{
    __shared__ float sts[NSTEPS + 1];
    __shared__ __align__(16) float sG[DX * DW];

    const int lane = threadIdx.x;       // blockDim = 64 (one wave)
    const int m16  = lane & 15;         // batch column of this lane
    const int quad = lane >> 4;
    const int r0   = blockIdx.x * 16;
    const int brow = r0 + m16;

    for (int i = lane; i <= NSTEPS; i += 64) sts[i] = ts[i];
    for (int i = lane; i < DX * DW; i += 64) sG[i] = G[i];
    __syncthreads();

    // slot j -> logical index within a 32-feature block
    int fo[8];
    #pragma unroll
    for (int j = 0; j < 8; ++j) fo[j] = (j < 4) ? (4 * quad + j) : (16 + 4 * quad + (j - 4));

    // ---- resident weight A-fragments (k pre-permuted; tanh layers pre-scaled by SC) ----
    bf8_t w1T[8];                        // SC*W1^T (x part, K=32)
    #pragma unroll
    for (int mt = 0; mt < 8; ++mt)
        #pragma unroll
        for (int j = 0; j < 8; ++j)
            w1T[mt][j] = (short)f2bf(SC * W1[(1 + fo[j]) * HDIM + mt * 16 + m16]);

    bf8_t w2T[8][4];                     // SC*W2^T (K=128: 4 k-tiles)
    #pragma unroll
    for (int mt = 0; mt < 8; ++mt)
        #pragma unroll
        for (int kt = 0; kt < 4; ++kt)
            #pragma unroll
            for (int j = 0; j < 8; ++j)
                w2T[mt][kt][j] = (short)f2bf(SC * W2[(kt * 32 + fo[j]) * HDIM + mt * 16 + m16]);

    bf8_t w3T[2][4];                     // W3^T (unscaled)
    #pragma unroll
    for (int mt = 0; mt < 2; ++mt)
        #pragma unroll
        for (int kt = 0; kt < 4; ++kt)
            #pragma unroll
            for (int j = 0; j < 8; ++j)
                w3T[mt][kt][j] = (short)f2bf(W3[(kt * 32 + fo[j]) * DW + mt * 16 + m16]);

    // L1 C-init state: cin = SC*(b1 + t*W1row0), updated incrementally by dt*w10v
    f4_t cin[8], w10v[8];
    {
        float t0 = ts[0];
        #pragma unroll
        for (int mt = 0; mt < 8; ++mt)
            #pragma unroll
            for (int i = 0; i < 4; ++i) {
                int f = mt * 16 + 4 * quad + i;
                float w = SC * W1[f];            // row 0 of W1 = t weights
                w10v[mt][i] = w;
                cin[mt][i]  = fmaf(t0, w, SC * b1[f]);
            }
    }
    // L2 bias (SC-scaled), packed bf16 pairs (unpacked per step, off critical path)
    unsigned b2p[16];
    #pragma unroll
    for (int mt = 0; mt < 8; ++mt) {
        int f0 = mt * 16 + 4 * quad;
        b2p[2 * mt]     = ((unsigned)f2bf(SC * b2[f0 + 1]) << 16) | f2bf(SC * b2[f0]);
        b2p[2 * mt + 1] = ((unsigned)f2bf(SC * b2[f0 + 3]) << 16) | f2bf(SC * b2[f0 + 2]);
    }
    f4_t b3C[2];
    f4_t bmu[2];        // BETA*mu
    float vtr[2][4];
    #pragma unroll
    for (int mt = 0; mt < 2; ++mt)
        #pragma unroll
        for (int i = 0; i < 4; ++i) {
            int f = mt * 16 + 4 * quad + i;
            b3C[mt][i] = b3[f];
            bmu[mt][i] = BETA * mu[f];
            vtr[mt][i] = vt[f];
        }

    // a = G G^T and G fragments (hi/lo split), A[row = m16 in tile mt][k = fo[j]]
    bf8_t ahi[2], alo[2], ghi[2], glo[2];
    #pragma unroll
    for (int mt = 0; mt < 2; ++mt) {
        float gb[32];
        const f4_t* pb = (const f4_t*)(sG + (mt * 16 + m16) * DW);
        #pragma unroll
        for (int k4 = 0; k4 < 8; ++k4) {
            f4_t t = pb[k4];
            gb[4 * k4] = t[0]; gb[4 * k4 + 1] = t[1]; gb[4 * k4 + 2] = t[2]; gb[4 * k4 + 3] = t[3];
        }
        #pragma unroll
        for (int j = 0; j < 8; ++j) {
            const f4_t* pa = (const f4_t*)(sG + fo[j] * DW);
            float acc = 0.f;
            #pragma unroll
            for (int k4 = 0; k4 < 8; ++k4) {
                f4_t t = pa[k4];
                acc += t[0] * gb[4 * k4] + t[1] * gb[4 * k4 + 1]
                     + t[2] * gb[4 * k4 + 2] + t[3] * gb[4 * k4 + 3];
            }
            unsigned short h = f2bf(acc);
            ahi[mt][j] = (short)h;
            alo[mt][j] = (short)f2bf(acc - bf2f(h));
            float gv = sG[(mt * 16 + m16) * DW + fo[j]];
            unsigned short hg = f2bf(gv);
            ghi[mt][j] = (short)hg;
            glo[mt][j] = (short)f2bf(gv - bf2f(hg));
        }
    }

    // ---- state ----
    float xr[2][4];
    {
        const f4_t* p = (const f4_t*)(x0 + (size_t)brow * DX);
        f4_t a = p[quad], b = p[4 + quad];
        #pragma unroll
        for (int i = 0; i < 4; ++i) { xr[0][i] = a[i]; xr[1][i] = b[i]; }
    }
    f4_t cw0, cw1;    // dW for current step
    {
        const f4_t* p = (const f4_t*)(dWs + (size_t)brow * DW);
        cw0 = p[quad]; cw1 = p[4 + quad];
    }

    const float T = sts[NSTEPS];
    float tcur = sts[0];
    float llr = 0.f;   // per-lane partial; reduced once after the loop

    float* xs_out = out;
    float* vs_out = out + (size_t)NSTEPS * BATCH * DX;
    float* ll_out = out + (size_t)2 * NSTEPS * BATCH * DX;

    #pragma unroll 2
    for (int s = 0; s < NSTEPS; ++s) {
        const float tnx    = sts[s + 1];
        const float dt     = tnx - tcur;
        const float sqdt   = __builtin_amdgcn_sqrtf(dt);
        const float invrem = rcp_hw(T - tcur + EPSG);

        // prefetch next step's dW (floats across the whole step body)
        f4_t nw0, nw1;
        {
            int sn = (s + 1 < NSTEPS) ? s + 1 : s;
            const f4_t* p = (const f4_t*)(dWs + (size_t)sn * (BATCH * DW) + (size_t)brow * DW);
            nw0 = p[quad]; nw1 = p[4 + quad];
        }

        // ---- gw = G @ (dW*sqrt(dt)): independent of x/v -> scheduled early ----
        U8 wh, wl;
        hilo_pk(cw0[0] * sqdt, cw0[1] * sqdt, wh.u[0], wl.u[0]);
        hilo_pk(cw0[2] * sqdt, cw0[3] * sqdt, wh.u[1], wl.u[1]);
        hilo_pk(cw1[0] * sqdt, cw1[1] * sqdt, wh.u[2], wl.u[2]);
        hilo_pk(cw1[2] * sqdt, cw1[3] * sqdt, wh.u[3], wl.u[3]);
        f4_t gw0 = {0, 0, 0, 0}, gw1 = {0, 0, 0, 0};
        gw0 = MFMA(ghi[0], wh.v, gw0);
        gw0 = MFMA(ghi[0], wl.v, gw0);
        gw0 = MFMA(glo[0], wh.v, gw0);
        gw1 = MFMA(ghi[1], wh.v, gw1);
        gw1 = MFMA(ghi[1], wl.v, gw1);
        gw1 = MFMA(glo[1], wh.v, gw1);

        // ---- r = (vt - x) * invrem, hi/lo fragment; ra = a @ r^T ----
        float r_[2][4];
        #pragma unroll
        for (int mt = 0; mt < 2; ++mt)
            #pragma unroll
            for (int i = 0; i < 4; ++i) r_[mt][i] = (vtr[mt][i] - xr[mt][i]) * invrem;
        U8 rh, rl;
        hilo_pk(r_[0][0], r_[0][1], rh.u[0], rl.u[0]);
        hilo_pk(r_[0][2], r_[0][3], rh.u[1], rl.u[1]);
        hilo_pk(r_[1][0], r_[1][1], rh.u[2], rl.u[2]);
        hilo_pk(r_[1][2], r_[1][3], rh.u[3], rl.u[3]);
        f4_t ra_[2];
        ra_[0] = f4_t{0, 0, 0, 0};
        ra_[0] = MFMA(ahi[0], rh.v, ra_[0]);
        ra_[0] = MFMA(ahi[0], rl.v, ra_[0]);
        ra_[0] = MFMA(alo[0], rh.v, ra_[0]);
        ra_[1] = f4_t{0, 0, 0, 0};
        ra_[1] = MFMA(ahi[1], rh.v, ra_[1]);
        ra_[1] = MFMA(ahi[1], rl.v, ra_[1]);
        ra_[1] = MFMA(alo[1], rh.v, ra_[1]);

        // ---- L1: acc = SC*(W1^T x + b1 + t*w10); tanh via exp2 ----
        U8 xb;
        xb.u[0] = cvtpk(xr[0][0], xr[0][1]); xb.u[1] = cvtpk(xr[0][2], xr[0][3]);
        xb.u[2] = cvtpk(xr[1][0], xr[1][1]); xb.u[3] = cvtpk(xr[1][2], xr[1][3]);

        U8 bh[4];
        #pragma unroll
        for (int mt = 0; mt < 8; ++mt) {
            f4_t acc = MFMA(w1T[mt], xb.v, cin[mt]);
            bh[mt >> 1].u[(2 * mt) & 3]     = cvtpk(tanh_s(acc[0]), tanh_s(acc[1]));
            bh[mt >> 1].u[(2 * mt + 1) & 3] = cvtpk(tanh_s(acc[2]), tanh_s(acc[3]));
        }

        // ---- L2 ----
        U8 bh2[4];
        #pragma unroll
        for (int mt = 0; mt < 8; ++mt) {
            unsigned ba = b2p[2 * mt], bb = b2p[2 * mt + 1];
            f4_t acc;
            acc[0] = unplo(ba); acc[1] = unphi(ba); acc[2] = unplo(bb); acc[3] = unphi(bb);
            #pragma unroll
            for (int kt = 0; kt < 4; ++kt) acc = MFMA(w2T[mt][kt], bh[kt].v, acc);
            bh2[mt >> 1].u[(2 * mt) & 3]     = cvtpk(tanh_s(acc[0]), tanh_s(acc[1]));
            bh2[mt >> 1].u[(2 * mt + 1) & 3] = cvtpk(tanh_s(acc[2]), tanh_s(acc[3]));
        }

        // ---- L3: v = W3^T h2 + b3 ----
        f4_t v0a = b3C[0], v1a = b3C[1];
        #pragma unroll
        for (int kt = 0; kt < 4; ++kt) {
            v0a = MFMA(w3T[0][kt], bh2[kt].v, v0a);
            v1a = MFMA(w3T[1][kt], bh2[kt].v, v1a);
        }

        // ---- xg = G@(v*dt) + gw : two parallel MFMA chains + add ----
        U8 uh, ul;
        hilo_pk(v0a[0] * dt, v0a[1] * dt, uh.u[0], ul.u[0]);
        hilo_pk(v0a[2] * dt, v0a[3] * dt, uh.u[1], ul.u[1]);
        hilo_pk(v1a[0] * dt, v1a[1] * dt, uh.u[2], ul.u[2]);
        hilo_pk(v1a[2] * dt, v1a[3] * dt, uh.u[3], ul.u[3]);
        f4_t xgA0 = MFMA(ghi[0], uh.v, gw0);
        f4_t xgB0 = {0, 0, 0, 0};
        xgB0 = MFMA(ghi[0], ul.v, xgB0);
        xgB0 = MFMA(glo[0], uh.v, xgB0);
        f4_t xgA1 = MFMA(ghi[1], uh.v, gw1);
        f4_t xgB1 = {0, 0, 0, 0};
        xgB1 = MFMA(ghi[1], ul.v, xgB1);
        xgB1 = MFMA(glo[1], uh.v, xgB1);
        f4_t xg_[2];
        xg_[0] = xgA0 + xgB0;
        xg_[1] = xgA1 + xgB1;

        // ---- Gval partial (per-lane, no shuffles) + x update + stores ----
        float gs = 0.f;
        f4_t xo[2], vo[2];
        vo[0] = v0a; vo[1] = v1a;
        #pragma unroll
        for (int mt = 0; mt < 2; ++mt)
            #pragma unroll
            for (int i = 0; i < 4; ++i) {
                float fb = fmaf(-BETA, xr[mt][i], bmu[mt][i]);
                gs = fmaf(fb, r_[mt][i], gs);
                gs = fmaf(-0.5f * r_[mt][i], ra_[mt][i], gs);
                float xn = fmaf(fb + ra_[mt][i], dt, xr[mt][i]) + xg_[mt][i];
                xr[mt][i] = xn;
                xo[mt][i] = xn;
            }
        llr = fmaf(gs, dt, llr);
        {
            f4_t* px = (f4_t*)(xs_out + (size_t)s * (BATCH * DX) + (size_t)brow * DX);
            px[quad]     = xo[0];
            px[4 + quad] = xo[1];
            f4_t* pv = (f4_t*)(vs_out + (size_t)s * (BATCH * DX) + (size_t)brow * DX);
            pv[quad]     = vo[0];
            pv[4 + quad] = vo[1];
        }

        // ---- roll state ----
        #pragma unroll
        for (int mt = 0; mt < 8; ++mt)
            #pragma unroll
            for (int i = 0; i < 4; ++i)
                cin[mt][i] = fmaf(dt, w10v[mt][i], cin[mt][i]);
        cw0 = nw0; cw1 = nw1;
        tcur = tnx;
    }

    // final ll reduce across the 4 quads of each batch column
    llr += __shfl_xor(llr, 16, 64);
    llr += __shfl_xor(llr, 32, 64);
    if (quad == 0) ll_out[brow] = llr;
}

extern "C" void kernel_launch(void* const* d_in, const int* in_sizes, int n_in,
                              void* d_out, int out_size, void* d_ws, size_t ws_size,
                              hipStream_t stream) {
    const float* x0 = (const float*)d_in[0];
    const float* ts = (const float*)d_in[1];
    const float* dWs = (const float*)d_in[2];
    const float* W1 = (const float*)d_in[3];
    const float* b1 = (const float*)d_in[4];
    const float* W2 = (const float*)d_in[5];
    const float* b2 = (const float*)d_in[6];
    const float* W3 = (const float*)d_in[7];
    const float* b3 = (const float*)d_in[8];
    const float* G  = (const float*)d_in[9];
    const float* mu = (const float*)d_in[10];
    const float* vt = (const float*)d_in[11];
    hipLaunchKernelGGL(sde_kernel, dim3(BATCH / 16), dim3(64), 0, stream,
                       x0, ts, dWs, W1, b1, W2, b2, W3, b3, G, mu, vt, (float*)d_out);
}

// Round 4
// 1061.146 us; speedup vs baseline: 1.9521x; 1.2626x over previous
//
#include <hip/hip_runtime.h>
#include <math.h>

#define NSTEPS 500
#define BATCH  1024
#define DX     32
#define DW     32
#define HDIM   128
#define BETA   0.5f
#define EPSG   1e-4f
#define SC     2.8853900817779268f   // 2*log2(e): pre-scale for exp2-based sigmoid

typedef short bf8_t __attribute__((ext_vector_type(8)));
typedef float f4_t  __attribute__((ext_vector_type(4)));

union U8 { bf8_t v; unsigned u[4]; };

__device__ __forceinline__ f4_t MFMA(bf8_t a, bf8_t b, f4_t c) {
    return __builtin_amdgcn_mfma_f32_16x16x32_bf16(a, b, c, 0, 0, 0);
}

__device__ __forceinline__ unsigned short f2bf(float x) {   // RNE f32->bf16
    unsigned u = __float_as_uint(x);
    u += 0x7fffu + ((u >> 16) & 1u);
    return (unsigned short)(u >> 16);
}
__device__ __forceinline__ float bf2f(unsigned short h) {
    return __uint_as_float(((unsigned)h) << 16);
}
// pack two f32 -> two bf16 in one u32 (lo = a, hi = b), RNE
__device__ __forceinline__ unsigned cvtpk(float a, float b) {
    unsigned r;
    asm("v_cvt_pk_bf16_f32 %0, %1, %2" : "=v"(r) : "v"(a), "v"(b));
    return r;
}
__device__ __forceinline__ float unplo(unsigned u) { return __uint_as_float(u << 16); }
__device__ __forceinline__ float unphi(unsigned u) { return __uint_as_float(u & 0xffff0000u); }

__device__ __forceinline__ float exp2_hw(float x) {
    float r; asm("v_exp_f32 %0, %1" : "=v"(r) : "v"(x)); return r;
}
__device__ __forceinline__ float rcp_hw(float x) {
    float r; asm("v_rcp_f32 %0, %1" : "=v"(r) : "v"(x)); return r;
}
// sg = 1/(2^zs + 1)  (zs = 2*log2(e)*z pre-folded).  tanh(z) = 1 - 2*sg, and the
// "1 - 2*" affine is folded into the NEXT layer's weights/bias.  Saturation-safe.
__device__ __forceinline__ float sigm_s(float zs) {
    return rcp_hw(exp2_hw(zs) + 1.f);
}

// hi/lo bf16 split of a pair via cvtpk
__device__ __forceinline__ void hilo_pk(float a, float b, unsigned& hp, unsigned& lp) {
    hp = cvtpk(a, b);
    lp = cvtpk(a - unplo(hp), b - unphi(hp));
}

// pin a bf16x8 fragment into the AGPR file (frees arch-VGPR budget; gfx950 MFMA
// reads A/B operands from AGPRs directly, so steady-state cost is ~zero)
__device__ __forceinline__ void agpr_pin(bf8_t& v) {
    asm("" : "+a"(v));
}

// ============================================================================
// Barrier-free: ONE wave owns 16 batch rows end-to-end, all transposed
// (batch = MFMA col = lane&15).  D-layout == next B-fragment layout under the
// k-slot permutation sigma(q,j) pre-applied to all weight A-fragments.
// Round 4: weights live in AGPRs (no scratch spills); tanh computed as
// sigma with the 1-2*sg affine folded into the next layer (colsums folded
// into f32 C-inits via a preamble ones-MFMA); dW folded into u (one pack).
// ============================================================================
__global__ __launch_bounds__(64, 1)
void sde_kernel(const float* __restrict__ x0, const float* __restrict__ ts,
                const float* __restrict__ dWs,
                const float* __restrict__ W1, const float* __restrict__ b1,
                const float* __restrict__ W2, const float* __restrict__ b2,
                const float* __restrict__ W3, const float* __restrict__ b3,
                const float* __restrict__ G,  const float* __restrict__ mu,
                const float* __restrict__ vt, float* __restrict__ out)
{
    __shared__ float sts[NSTEPS + 1];
    __shared__ __align__(16) float sG[DX * DW];

    const int lane = threadIdx.x;       // blockDim = 64 (one wave)
    const int m16  = lane & 15;         // batch column of this lane
    const int quad = lane >> 4;
    const int r0   = blockIdx.x * 16;
    const int brow = r0 + m16;

    for (int i = lane; i <= NSTEPS; i += 64) sts[i] = ts[i];
    for (int i = lane; i < DX * DW; i += 64) sG[i] = G[i];
    __syncthreads();

    // slot j -> logical index within a 32-feature block
    int fo[8];
    #pragma unroll
    for (int j = 0; j < 8; ++j) fo[j] = (j < 4) ? (4 * quad + j) : (16 + 4 * quad + (j - 4));

    // ---- weight A-fragments -> AGPRs.  w2/w3 carry the sigmoid fold (-2 factor). ----
    bf8_t w1a[8];                        // SC*W1^T (x part, K=32)
    #pragma unroll
    for (int mt = 0; mt < 8; ++mt) {
        #pragma unroll
        for (int j = 0; j < 8; ++j)
            w1a[mt][j] = (short)f2bf(SC * W1[(1 + fo[j]) * HDIM + mt * 16 + m16]);
        agpr_pin(w1a[mt]);
    }
    bf8_t w2a[8][4];                     // -2*SC*W2^T (K=128: 4 k-tiles)
    #pragma unroll
    for (int mt = 0; mt < 8; ++mt)
        #pragma unroll
        for (int kt = 0; kt < 4; ++kt) {
            #pragma unroll
            for (int j = 0; j < 8; ++j)
                w2a[mt][kt][j] = (short)f2bf(-2.f * SC * W2[(kt * 32 + fo[j]) * HDIM + mt * 16 + m16]);
            agpr_pin(w2a[mt][kt]);
        }
    bf8_t w3a[2][4];                     // -2*W3^T
    #pragma unroll
    for (int mt = 0; mt < 2; ++mt)
        #pragma unroll
        for (int kt = 0; kt < 4; ++kt) {
            #pragma unroll
            for (int j = 0; j < 8; ++j)
                w3a[mt][kt][j] = (short)f2bf(-2.f * W3[(kt * 32 + fo[j]) * DW + mt * 16 + m16]);
            agpr_pin(w3a[mt][kt]);
        }

    // all-ones bf16 fragment (for colsum folding, consistent with frag rounding)
    bf8_t ones;
    #pragma unroll
    for (int j = 0; j < 8; ++j) ones[j] = (short)0x3f80;

    // ---- f32 C-inits with folded colsums:  b2C = SC*b2 - 0.5*Sum(w2a·1),
    //      b3C = b3 - 0.5*Sum(w3a·1)  (Sum rows = -2*scale*colsum) ----
    f4_t b2C[8];
    #pragma unroll
    for (int mt = 0; mt < 8; ++mt) {
        f4_t S = {0, 0, 0, 0};
        #pragma unroll
        for (int kt = 0; kt < 4; ++kt) S = MFMA(w2a[mt][kt], ones, S);
        #pragma unroll
        for (int i = 0; i < 4; ++i)
            b2C[mt][i] = fmaf(-0.5f, S[i], SC * b2[mt * 16 + 4 * quad + i]);
    }
    f4_t b3C[2];
    #pragma unroll
    for (int mt = 0; mt < 2; ++mt) {
        f4_t S = {0, 0, 0, 0};
        #pragma unroll
        for (int kt = 0; kt < 4; ++kt) S = MFMA(w3a[mt][kt], ones, S);
        #pragma unroll
        for (int i = 0; i < 4; ++i)
            b3C[mt][i] = fmaf(-0.5f, S[i], b3[mt * 16 + 4 * quad + i]);
    }

    // L1 C-init state: cin = SC*(b1 + t*W1row0); rolled by dt * w10 (packed bf16)
    f4_t cin[8];
    unsigned w10p[16];
    {
        float t0 = ts[0];
        #pragma unroll
        for (int mt = 0; mt < 8; ++mt) {
            int f0 = mt * 16 + 4 * quad;
            float wa = SC * W1[f0],     wb = SC * W1[f0 + 1];
            float wc = SC * W1[f0 + 2], wd = SC * W1[f0 + 3];
            w10p[2 * mt]     = ((unsigned)f2bf(wb) << 16) | f2bf(wa);
            w10p[2 * mt + 1] = ((unsigned)f2bf(wd) << 16) | f2bf(wc);
            cin[mt][0] = fmaf(t0, wa, SC * b1[f0]);
            cin[mt][1] = fmaf(t0, wb, SC * b1[f0 + 1]);
            cin[mt][2] = fmaf(t0, wc, SC * b1[f0 + 2]);
            cin[mt][3] = fmaf(t0, wd, SC * b1[f0 + 3]);
        }
    }

    f4_t bmu[2];        // BETA*mu
    float vtr[2][4];
    #pragma unroll
    for (int mt = 0; mt < 2; ++mt)
        #pragma unroll
        for (int i = 0; i < 4; ++i) {
            int f = mt * 16 + 4 * quad + i;
            bmu[mt][i] = BETA * mu[f];
            vtr[mt][i] = vt[f];
        }

    // a = G G^T and G fragments (hi/lo split), A[row = m16 in tile mt][k = fo[j]]
    bf8_t ahi[2], alo[2], ghi[2], glo[2];
    #pragma unroll
    for (int mt = 0; mt < 2; ++mt) {
        float gb[32];
        const f4_t* pb = (const f4_t*)(sG + (mt * 16 + m16) * DW);
        #pragma unroll
        for (int k4 = 0; k4 < 8; ++k4) {
            f4_t t = pb[k4];
            gb[4 * k4] = t[0]; gb[4 * k4 + 1] = t[1]; gb[4 * k4 + 2] = t[2]; gb[4 * k4 + 3] = t[3];
        }
        #pragma unroll
        for (int j = 0; j < 8; ++j) {
            const f4_t* pa = (const f4_t*)(sG + fo[j] * DW);
            float acc = 0.f;
            #pragma unroll
            for (int k4 = 0; k4 < 8; ++k4) {
                f4_t t = pa[k4];
                acc += t[0] * gb[4 * k4] + t[1] * gb[4 * k4 + 1]
                     + t[2] * gb[4 * k4 + 2] + t[3] * gb[4 * k4 + 3];
            }
            unsigned short h = f2bf(acc);
            ahi[mt][j] = (short)h;
            alo[mt][j] = (short)f2bf(acc - bf2f(h));
            float gv = sG[(mt * 16 + m16) * DW + fo[j]];
            unsigned short hg = f2bf(gv);
            ghi[mt][j] = (short)hg;
            glo[mt][j] = (short)f2bf(gv - bf2f(hg));
        }
    }

    // ---- state ----
    float xr[2][4];
    {
        const f4_t* p = (const f4_t*)(x0 + (size_t)brow * DX);
        f4_t a = p[quad], b = p[4 + quad];
        #pragma unroll
        for (int i = 0; i < 4; ++i) { xr[0][i] = a[i]; xr[1][i] = b[i]; }
    }
    f4_t cw0, cw1;    // dW for current step
    {
        const f4_t* p = (const f4_t*)(dWs + (size_t)brow * DW);
        cw0 = p[quad]; cw1 = p[4 + quad];
    }

    const float T = sts[NSTEPS];
    float tcur = sts[0];
    float llr = 0.f;   // per-lane partial; reduced once after the loop

    float* xs_out = out;
    float* vs_out = out + (size_t)NSTEPS * BATCH * DX;
    float* ll_out = out + (size_t)2 * NSTEPS * BATCH * DX;

    #pragma unroll 1
    for (int s = 0; s < NSTEPS; ++s) {
        const float tnx    = sts[s + 1];
        const float dt     = tnx - tcur;
        const float sqdt   = __builtin_amdgcn_sqrtf(dt);
        const float invrem = rcp_hw(T - tcur + EPSG);

        // prefetch next step's dW (floats across the whole step body)
        f4_t nw0, nw1;
        {
            int sn = (s + 1 < NSTEPS) ? s + 1 : s;
            const f4_t* p = (const f4_t*)(dWs + (size_t)sn * (BATCH * DW) + (size_t)brow * DW);
            nw0 = p[quad]; nw1 = p[4 + quad];
        }

        // ---- r = (vt - x) * invrem, hi/lo fragment; ra = a @ r^T ----
        float r_[2][4];
        #pragma unroll
        for (int mt = 0; mt < 2; ++mt)
            #pragma unroll
            for (int i = 0; i < 4; ++i) r_[mt][i] = (vtr[mt][i] - xr[mt][i]) * invrem;
        U8 rh, rl;
        hilo_pk(r_[0][0], r_[0][1], rh.u[0], rl.u[0]);
        hilo_pk(r_[0][2], r_[0][3], rh.u[1], rl.u[1]);
        hilo_pk(r_[1][0], r_[1][1], rh.u[2], rl.u[2]);
        hilo_pk(r_[1][2], r_[1][3], rh.u[3], rl.u[3]);
        f4_t ra_[2];
        ra_[0] = f4_t{0, 0, 0, 0};
        ra_[0] = MFMA(ahi[0], rh.v, ra_[0]);
        ra_[0] = MFMA(ahi[0], rl.v, ra_[0]);
        ra_[0] = MFMA(alo[0], rh.v, ra_[0]);
        ra_[1] = f4_t{0, 0, 0, 0};
        ra_[1] = MFMA(ahi[1], rh.v, ra_[1]);
        ra_[1] = MFMA(ahi[1], rl.v, ra_[1]);
        ra_[1] = MFMA(alo[1], rh.v, ra_[1]);

        // ---- L1: acc = SC*(W1^T x + b1 + t*w10); sg1 = 1/(2^acc+1) ----
        U8 xb;
        xb.u[0] = cvtpk(xr[0][0], xr[0][1]); xb.u[1] = cvtpk(xr[0][2], xr[0][3]);
        xb.u[2] = cvtpk(xr[1][0], xr[1][1]); xb.u[3] = cvtpk(xr[1][2], xr[1][3]);

        U8 bh[4];
        #pragma unroll
        for (int mt = 0; mt < 8; ++mt) {
            f4_t acc = MFMA(w1a[mt], xb.v, cin[mt]);
            bh[mt >> 1].u[(2 * mt) & 3]     = cvtpk(sigm_s(acc[0]), sigm_s(acc[1]));
            bh[mt >> 1].u[(2 * mt + 1) & 3] = cvtpk(sigm_s(acc[2]), sigm_s(acc[3]));
        }

        // ---- L2 (weights carry -2*SC fold; C-init carries colsum) ----
        U8 bh2[4];
        #pragma unroll
        for (int mt = 0; mt < 8; ++mt) {
            f4_t acc = b2C[mt];
            #pragma unroll
            for (int kt = 0; kt < 4; ++kt) acc = MFMA(w2a[mt][kt], bh[kt].v, acc);
            bh2[mt >> 1].u[(2 * mt) & 3]     = cvtpk(sigm_s(acc[0]), sigm_s(acc[1]));
            bh2[mt >> 1].u[(2 * mt + 1) & 3] = cvtpk(sigm_s(acc[2]), sigm_s(acc[3]));
        }

        // ---- L3: v = (-2W3)^T sg2 + (b3 + colsum3) ----
        f4_t v0a = b3C[0], v1a = b3C[1];
        #pragma unroll
        for (int kt = 0; kt < 4; ++kt) {
            v0a = MFMA(w3a[0][kt], bh2[kt].v, v0a);
            v1a = MFMA(w3a[1][kt], bh2[kt].v, v1a);
        }

        // ---- u = v*dt + dW*sqrt(dt); xg = G @ u^T (hi/lo) ----
        float u_[2][4];
        #pragma unroll
        for (int i = 0; i < 4; ++i) {
            u_[0][i] = fmaf(v0a[i], dt, cw0[i] * sqdt);
            u_[1][i] = fmaf(v1a[i], dt, cw1[i] * sqdt);
        }
        U8 uh, ul;
        hilo_pk(u_[0][0], u_[0][1], uh.u[0], ul.u[0]);
        hilo_pk(u_[0][2], u_[0][3], uh.u[1], ul.u[1]);
        hilo_pk(u_[1][0], u_[1][1], uh.u[2], ul.u[2]);
        hilo_pk(u_[1][2], u_[1][3], uh.u[3], ul.u[3]);
        f4_t xg0 = {0, 0, 0, 0}, xg1 = {0, 0, 0, 0};
        xg0 = MFMA(ghi[0], uh.v, xg0);
        xg0 = MFMA(ghi[0], ul.v, xg0);
        xg0 = MFMA(glo[0], uh.v, xg0);
        xg1 = MFMA(ghi[1], uh.v, xg1);
        xg1 = MFMA(ghi[1], ul.v, xg1);
        xg1 = MFMA(glo[1], uh.v, xg1);
        f4_t xg_[2]; xg_[0] = xg0; xg_[1] = xg1;

        // ---- Gval partial (per-lane, no shuffles) + x update + stores ----
        float gs = 0.f;
        f4_t xo[2];
        #pragma unroll
        for (int mt = 0; mt < 2; ++mt)
            #pragma unroll
            for (int i = 0; i < 4; ++i) {
                float fb = fmaf(-BETA, xr[mt][i], bmu[mt][i]);
                gs = fmaf(fb, r_[mt][i], gs);
                gs = fmaf(-0.5f * r_[mt][i], ra_[mt][i], gs);
                float xn = fmaf(fb + ra_[mt][i], dt, xr[mt][i]) + xg_[mt][i];
                xr[mt][i] = xn;
                xo[mt][i] = xn;
            }
        llr = fmaf(gs, dt, llr);
        {
            f4_t* px = (f4_t*)(xs_out + (size_t)s * (BATCH * DX) + (size_t)brow * DX);
            px[quad]     = xo[0];
            px[4 + quad] = xo[1];
            f4_t* pv = (f4_t*)(vs_out + (size_t)s * (BATCH * DX) + (size_t)brow * DX);
            pv[quad]     = v0a;
            pv[4 + quad] = v1a;
        }

        // ---- roll state: cin += dt * w10 (unpacked bf16) ----
        #pragma unroll
        for (int mt = 0; mt < 8; ++mt) {
            unsigned wa = w10p[2 * mt], wb = w10p[2 * mt + 1];
            cin[mt][0] = fmaf(dt, unplo(wa), cin[mt][0]);
            cin[mt][1] = fmaf(dt, unphi(wa), cin[mt][1]);
            cin[mt][2] = fmaf(dt, unplo(wb), cin[mt][2]);
            cin[mt][3] = fmaf(dt, unphi(wb), cin[mt][3]);
        }
        cw0 = nw0; cw1 = nw1;
        tcur = tnx;
    }

    // final ll reduce across the 4 quads of each batch column
    llr += __shfl_xor(llr, 16, 64);
    llr += __shfl_xor(llr, 32, 64);
    if (quad == 0) ll_out[brow] = llr;
}

extern "C" void kernel_launch(void* const* d_in, const int* in_sizes, int n_in,
                              void* d_out, int out_size, void* d_ws, size_t ws_size,
                              hipStream_t stream) {
    const float* x0 = (const float*)d_in[0];
    const float* ts = (const float*)d_in[1];
    const float* dWs = (const float*)d_in[2];
    const float* W1 = (const float*)d_in[3];
    const float* b1 = (const float*)d_in[4];
    const float* W2 = (const float*)d_in[5];
    const float* b2 = (const float*)d_in[6];
    const float* W3 = (const float*)d_in[7];
    const float* b3 = (const float*)d_in[8];
    const float* G  = (const float*)d_in[9];
    const float* mu = (const float*)d_in[10];
    const float* vt = (const float*)d_in[11];
    hipLaunchKernelGGL(sde_kernel, dim3(BATCH / 16), dim3(64), 0, stream,
                       x0, ts, dWs, W1, b1, W2, b2, W3, b3, G, mu, vt, (float*)d_out);
}

// Round 5
// 857.020 us; speedup vs baseline: 2.4171x; 1.2382x over previous
//
#include <hip/hip_runtime.h>
#include <math.h>

#define NSTEPS 500
#define BATCH  1024
#define DX     32
#define DW     32
#define HDIM   128
#define BETA   0.5f
#define EPSG   1e-4f
#define SC     2.8853900817779268f   // 2*log2(e): pre-scale for exp2-based sigmoid

typedef short bf8_t __attribute__((ext_vector_type(8)));
typedef float f4_t  __attribute__((ext_vector_type(4)));

union U8 { bf8_t v; unsigned u[4]; };

__device__ __forceinline__ f4_t MFMA(bf8_t a, bf8_t b, f4_t c) {
    return __builtin_amdgcn_mfma_f32_16x16x32_bf16(a, b, c, 0, 0, 0);
}

__device__ __forceinline__ unsigned short f2bf(float x) {   // RNE f32->bf16
    unsigned u = __float_as_uint(x);
    u += 0x7fffu + ((u >> 16) & 1u);
    return (unsigned short)(u >> 16);
}
__device__ __forceinline__ float bf2f(unsigned short h) {
    return __uint_as_float(((unsigned)h) << 16);
}
__device__ __forceinline__ unsigned cvtpk(float a, float b) {
    unsigned r;
    asm("v_cvt_pk_bf16_f32 %0, %1, %2" : "=v"(r) : "v"(a), "v"(b));
    return r;
}
__device__ __forceinline__ float unplo(unsigned u) { return __uint_as_float(u << 16); }
__device__ __forceinline__ float unphi(unsigned u) { return __uint_as_float(u & 0xffff0000u); }

__device__ __forceinline__ float exp2_hw(float x) {
    float r; asm("v_exp_f32 %0, %1" : "=v"(r) : "v"(x)); return r;
}
__device__ __forceinline__ float rcp_hw(float x) {
    float r; asm("v_rcp_f32 %0, %1" : "=v"(r) : "v"(x)); return r;
}
// sg = 1/(2^zs + 1); tanh(z) = 1 - 2*sg folded into next layer's weights/bias
__device__ __forceinline__ float sigm_s(float zs) {
    return rcp_hw(exp2_hw(zs) + 1.f);
}
__device__ __forceinline__ void hilo_pk(float a, float b, unsigned& hp, unsigned& lp) {
    hp = cvtpk(a, b);
    lp = cvtpk(a - unplo(hp), b - unphi(hp));
}
__device__ __forceinline__ void agpr_pin(bf8_t& v) { asm("" : "+a"(v)); }

// LDS barrier: orders LDS (lgkmcnt) but lets global loads/stores float across.
__device__ __forceinline__ void bar_lds() {
    __builtin_amdgcn_sched_barrier(0);
    asm volatile("s_waitcnt lgkmcnt(0)" ::: "memory");
    __builtin_amdgcn_s_barrier();
    __builtin_amdgcn_sched_barrier(0);
}

// ============================================================================
// 2-wave feature-split of the round-4 barrier-free design.  One block = 2
// waves = one 16-row batch tile.  Wave w owns: H-features [64w,64w+64) for
// L1/L2, and DX/DW half [16w,16w+16) for x-state, r, ra, v, u, xg, Gval.
// Per-wave k-slot maps put OWN half in slots j<4 (k-tiles 0,1) and PARTNER
// half in j>=4 (k-tiles 2,3), baked into each wave's weight A-fragments, so
// all exchanges are same-lane LDS copies with zero shuffling.  4 exchanges/
// step (x+r packs, h1, h2, u packs), 4 barriers, single-buffered (writes and
// reads of each buffer are >=3 barriers apart).  Weights in AGPRs.
// ============================================================================
__global__ __launch_bounds__(128, 1)
void sde_kernel(const float* __restrict__ x0, const float* __restrict__ ts,
                const float* __restrict__ dWs,
                const float* __restrict__ W1, const float* __restrict__ b1,
                const float* __restrict__ W2, const float* __restrict__ b2,
                const float* __restrict__ W3, const float* __restrict__ b3,
                const float* __restrict__ G,  const float* __restrict__ mu,
                const float* __restrict__ vt, float* __restrict__ out)
{
    __shared__ float sts[NSTEPS + 1];
    __shared__ __align__(16) float sG[DX * DW];
    __shared__ __align__(16) unsigned sXB[2][64][2];
    __shared__ __align__(16) unsigned sRH[2][64][2];
    __shared__ __align__(16) unsigned sRL[2][64][2];
    __shared__ __align__(16) unsigned sBH[4][64][4];
    __shared__ __align__(16) unsigned sB2[4][64][4];
    __shared__ __align__(16) unsigned sUH[2][64][2];
    __shared__ __align__(16) unsigned sUL[2][64][2];
    __shared__ float sLL[2][16];

    const int tid  = threadIdx.x;
    const int w    = tid >> 6;       // wave id (0/1)
    const int ow   = 1 - w;
    const int lane = tid & 63;
    const int m16  = lane & 15;      // batch column of this lane
    const int quad = lane >> 4;
    const int r0   = blockIdx.x * 16;
    const int brow = r0 + m16;

    for (int i = tid; i <= NSTEPS; i += 128) sts[i] = ts[i];
    for (int i = tid; i < DX * DW; i += 128) sG[i] = G[i];
    __syncthreads();

    // k-slot maps.  foS: group-local standard sigma (H-axis, 32-wide groups).
    // foW: DX/DW axis (32 total), own 16-half in slots j<4, partner in j>=4.
    int foS[8], foW[8], ktG[4];
    #pragma unroll
    for (int j = 0; j < 8; ++j) {
        foS[j] = (j < 4) ? (4 * quad + j) : (16 + 4 * quad + (j - 4));
        foW[j] = ((j < 4) ? w * 16 : ow * 16) + 4 * quad + (j & 3);
    }
    ktG[0] = 2 * w; ktG[1] = 2 * w + 1; ktG[2] = 2 * ow; ktG[3] = 2 * ow + 1;

    // ---- weight A-fragments (own shares only) -> AGPRs ----
    bf8_t w1a[4];                        // SC*W1^T (x part), own H-quarter mts
    #pragma unroll
    for (int ml = 0; ml < 4; ++ml) {
        int mtg = 4 * w + ml;
        #pragma unroll
        for (int j = 0; j < 8; ++j)
            w1a[ml][j] = (short)f2bf(SC * W1[(1 + foW[j]) * HDIM + mtg * 16 + m16]);
        agpr_pin(w1a[ml]);
    }
    bf8_t w2a[4][4];                     // -2*SC*W2^T, K order = ktG
    #pragma unroll
    for (int ml = 0; ml < 4; ++ml) {
        int mtg = 4 * w + ml;
        #pragma unroll
        for (int kf = 0; kf < 4; ++kf) {
            #pragma unroll
            for (int j = 0; j < 8; ++j)
                w2a[ml][kf][j] = (short)f2bf(-2.f * SC * W2[(ktG[kf] * 32 + foS[j]) * HDIM + mtg * 16 + m16]);
            agpr_pin(w2a[ml][kf]);
        }
    }
    bf8_t w3a[4];                        // -2*W3^T, own DW-half outputs
    #pragma unroll
    for (int kf = 0; kf < 4; ++kf) {
        #pragma unroll
        for (int j = 0; j < 8; ++j)
            w3a[kf][j] = (short)f2bf(-2.f * W3[(ktG[kf] * 32 + foS[j]) * DW + w * 16 + m16]);
        agpr_pin(w3a[kf]);
    }

    bf8_t ones;
    #pragma unroll
    for (int j = 0; j < 8; ++j) ones[j] = (short)0x3f80;

    // folded C-inits: b2C = SC*b2 - 0.5*Sum(w2a), b3C = b3 - 0.5*Sum(w3a)
    f4_t b2C[4];
    #pragma unroll
    for (int ml = 0; ml < 4; ++ml) {
        f4_t S = {0, 0, 0, 0};
        #pragma unroll
        for (int kf = 0; kf < 4; ++kf) S = MFMA(w2a[ml][kf], ones, S);
        #pragma unroll
        for (int i = 0; i < 4; ++i)
            b2C[ml][i] = fmaf(-0.5f, S[i], SC * b2[(4 * w + ml) * 16 + 4 * quad + i]);
    }
    f4_t b3C;
    {
        f4_t S = {0, 0, 0, 0};
        #pragma unroll
        for (int kf = 0; kf < 4; ++kf) S = MFMA(w3a[kf], ones, S);
        #pragma unroll
        for (int i = 0; i < 4; ++i)
            b3C[i] = fmaf(-0.5f, S[i], b3[w * 16 + 4 * quad + i]);
    }

    // L1 C-init state: cin = SC*(b1 + t*W1row0), rolled by dt*w10 (own mts)
    f4_t cin[4];
    unsigned w10p[8];
    {
        float t0 = ts[0];
        #pragma unroll
        for (int ml = 0; ml < 4; ++ml) {
            int f0 = (4 * w + ml) * 16 + 4 * quad;
            float wa = SC * W1[f0],     wb = SC * W1[f0 + 1];
            float wc = SC * W1[f0 + 2], wd = SC * W1[f0 + 3];
            w10p[2 * ml]     = ((unsigned)f2bf(wb) << 16) | f2bf(wa);
            w10p[2 * ml + 1] = ((unsigned)f2bf(wd) << 16) | f2bf(wc);
            cin[ml][0] = fmaf(t0, wa, SC * b1[f0]);
            cin[ml][1] = fmaf(t0, wb, SC * b1[f0 + 1]);
            cin[ml][2] = fmaf(t0, wc, SC * b1[f0 + 2]);
            cin[ml][3] = fmaf(t0, wd, SC * b1[f0 + 3]);
        }
    }

    f4_t bmu;           // BETA*mu, own DX half
    float vtr[4];
    #pragma unroll
    for (int i = 0; i < 4; ++i) {
        int f = w * 16 + 4 * quad + i;
        bmu[i] = BETA * mu[f];
        vtr[i] = vt[f];
    }

    // a = G G^T and G fragments (hi/lo), own DX-half rows, k order = foW
    bf8_t ahi, alo, ghi, glo;
    {
        int rowA = w * 16 + m16;
        float gb[32];
        const f4_t* pb = (const f4_t*)(sG + rowA * DW);
        #pragma unroll
        for (int k4 = 0; k4 < 8; ++k4) {
            f4_t t = pb[k4];
            gb[4 * k4] = t[0]; gb[4 * k4 + 1] = t[1]; gb[4 * k4 + 2] = t[2]; gb[4 * k4 + 3] = t[3];
        }
        #pragma unroll
        for (int j = 0; j < 8; ++j) {
            const f4_t* pa = (const f4_t*)(sG + foW[j] * DW);
            float acc = 0.f;
            #pragma unroll
            for (int k4 = 0; k4 < 8; ++k4) {
                f4_t t = pa[k4];
                acc += t[0] * gb[4 * k4] + t[1] * gb[4 * k4 + 1]
                     + t[2] * gb[4 * k4 + 2] + t[3] * gb[4 * k4 + 3];
            }
            unsigned short h = f2bf(acc);
            ahi[j] = (short)h;
            alo[j] = (short)f2bf(acc - bf2f(h));
            float gv = sG[rowA * DW + foW[j]];
            unsigned short hg = f2bf(gv);
            ghi[j] = (short)hg;
            glo[j] = (short)f2bf(gv - bf2f(hg));
        }
    }

    // ---- state (own DX/DW half: features/dims w*16 + 4*quad + i) ----
    f4_t xr = ((const f4_t*)(x0 + (size_t)brow * DX))[w * 4 + quad];
    f4_t cw = ((const f4_t*)(dWs + (size_t)brow * DW))[w * 4 + quad];

    const float T = sts[NSTEPS];
    float tcur = sts[0];
    float llr = 0.f;

    float* xs_out = out;
    float* vs_out = out + (size_t)NSTEPS * BATCH * DX;
    float* ll_out = out + (size_t)2 * NSTEPS * BATCH * DX;

    #pragma unroll 1
    for (int s = 0; s < NSTEPS; ++s) {
        const float tnx    = sts[s + 1];
        const float dt     = tnx - tcur;
        const float sqdt   = __builtin_amdgcn_sqrtf(dt);
        const float invrem = rcp_hw(T - tcur + EPSG);

        // prefetch next step's dW (own half; floats across the step)
        f4_t nw;
        {
            int sn = (s + 1 < NSTEPS) ? s + 1 : s;
            nw = ((const f4_t*)(dWs + (size_t)sn * (BATCH * DW) + (size_t)brow * DW))[w * 4 + quad];
        }

        // ---- own r + packs; exchange X0 = {xb, rh, rl} halves ----
        float rr[4];
        #pragma unroll
        for (int i = 0; i < 4; ++i) rr[i] = (vtr[i] - xr[i]) * invrem;
        unsigned rh0, rh1, rl0, rl1;
        hilo_pk(rr[0], rr[1], rh0, rl0);
        hilo_pk(rr[2], rr[3], rh1, rl1);
        unsigned xb0 = cvtpk(xr[0], xr[1]), xb1 = cvtpk(xr[2], xr[3]);
        *(uint2*)&sXB[w][lane][0] = make_uint2(xb0, xb1);
        *(uint2*)&sRH[w][lane][0] = make_uint2(rh0, rh1);
        *(uint2*)&sRL[w][lane][0] = make_uint2(rl0, rl1);
        bar_lds();   // 1
        uint2 pxb = *(const uint2*)&sXB[ow][lane][0];
        uint2 prh = *(const uint2*)&sRH[ow][lane][0];
        uint2 prl = *(const uint2*)&sRL[ow][lane][0];
        U8 xbF, rhF, rlF;
        xbF.u[0] = xb0; xbF.u[1] = xb1; xbF.u[2] = pxb.x; xbF.u[3] = pxb.y;
        rhF.u[0] = rh0; rhF.u[1] = rh1; rhF.u[2] = prh.x; rhF.u[3] = prh.y;
        rlF.u[0] = rl0; rlF.u[1] = rl1; rlF.u[2] = prl.x; rlF.u[3] = prl.y;

        // ---- L1 (own 4 mts) ----
        U8 bhO[2];
        #pragma unroll
        for (int ml = 0; ml < 4; ++ml) {
            f4_t acc = MFMA(w1a[ml], xbF.v, cin[ml]);
            bhO[ml >> 1].u[(2 * ml) & 3]     = cvtpk(sigm_s(acc[0]), sigm_s(acc[1]));
            bhO[ml >> 1].u[(2 * ml + 1) & 3] = cvtpk(sigm_s(acc[2]), sigm_s(acc[3]));
        }
        // ra = a @ r^T (own DX-half rows)
        f4_t ra = {0, 0, 0, 0};
        ra = MFMA(ahi, rhF.v, ra);
        ra = MFMA(ahi, rlF.v, ra);
        ra = MFMA(alo, rhF.v, ra);

        *(uint4*)&sBH[2 * w][lane][0]     = make_uint4(bhO[0].u[0], bhO[0].u[1], bhO[0].u[2], bhO[0].u[3]);
        *(uint4*)&sBH[2 * w + 1][lane][0] = make_uint4(bhO[1].u[0], bhO[1].u[1], bhO[1].u[2], bhO[1].u[3]);
        bar_lds();   // 2
        U8 bhF2, bhF3;
        {
            uint4 t2 = *(const uint4*)&sBH[2 * ow][lane][0];
            uint4 t3 = *(const uint4*)&sBH[2 * ow + 1][lane][0];
            bhF2.u[0] = t2.x; bhF2.u[1] = t2.y; bhF2.u[2] = t2.z; bhF2.u[3] = t2.w;
            bhF3.u[0] = t3.x; bhF3.u[1] = t3.y; bhF3.u[2] = t3.z; bhF3.u[3] = t3.w;
        }

        // ---- L2 (own 4 mts; K order = ktG: own tiles first) ----
        U8 b2O[2];
        #pragma unroll
        for (int ml = 0; ml < 4; ++ml) {
            f4_t acc = b2C[ml];
            acc = MFMA(w2a[ml][0], bhO[0].v, acc);
            acc = MFMA(w2a[ml][1], bhO[1].v, acc);
            acc = MFMA(w2a[ml][2], bhF2.v, acc);
            acc = MFMA(w2a[ml][3], bhF3.v, acc);
            b2O[ml >> 1].u[(2 * ml) & 3]     = cvtpk(sigm_s(acc[0]), sigm_s(acc[1]));
            b2O[ml >> 1].u[(2 * ml + 1) & 3] = cvtpk(sigm_s(acc[2]), sigm_s(acc[3]));
        }
        *(uint4*)&sB2[2 * w][lane][0]     = make_uint4(b2O[0].u[0], b2O[0].u[1], b2O[0].u[2], b2O[0].u[3]);
        *(uint4*)&sB2[2 * w + 1][lane][0] = make_uint4(b2O[1].u[0], b2O[1].u[1], b2O[1].u[2], b2O[1].u[3]);
        bar_lds();   // 3
        U8 b2F2, b2F3;
        {
            uint4 t2 = *(const uint4*)&sB2[2 * ow][lane][0];
            uint4 t3 = *(const uint4*)&sB2[2 * ow + 1][lane][0];
            b2F2.u[0] = t2.x; b2F2.u[1] = t2.y; b2F2.u[2] = t2.z; b2F2.u[3] = t2.w;
            b2F3.u[0] = t3.x; b2F3.u[1] = t3.y; b2F3.u[2] = t3.z; b2F3.u[3] = t3.w;
        }

        // ---- L3: own 16 outputs ----
        f4_t vA = b3C;
        vA = MFMA(w3a[0], b2O[0].v, vA);
        vA = MFMA(w3a[1], b2O[1].v, vA);
        vA = MFMA(w3a[2], b2F2.v, vA);
        vA = MFMA(w3a[3], b2F3.v, vA);

        // ---- u = v*dt + dW*sqrt(dt) (own half); exchange packs ----
        float u_[4];
        #pragma unroll
        for (int i = 0; i < 4; ++i) u_[i] = fmaf(vA[i], dt, cw[i] * sqdt);
        unsigned uh0, uh1, ul0, ul1;
        hilo_pk(u_[0], u_[1], uh0, ul0);
        hilo_pk(u_[2], u_[3], uh1, ul1);
        *(uint2*)&sUH[w][lane][0] = make_uint2(uh0, uh1);
        *(uint2*)&sUL[w][lane][0] = make_uint2(ul0, ul1);
        bar_lds();   // 4
        uint2 puh = *(const uint2*)&sUH[ow][lane][0];
        uint2 pul = *(const uint2*)&sUL[ow][lane][0];
        U8 uhF, ulF;
        uhF.u[0] = uh0; uhF.u[1] = uh1; uhF.u[2] = puh.x; uhF.u[3] = puh.y;
        ulF.u[0] = ul0; ulF.u[1] = ul1; ulF.u[2] = pul.x; ulF.u[3] = pul.y;

        // ---- xg = G @ u^T (own DX-half rows) ----
        f4_t xg = {0, 0, 0, 0};
        xg = MFMA(ghi, uhF.v, xg);
        xg = MFMA(ghi, ulF.v, xg);
        xg = MFMA(glo, uhF.v, xg);

        // ---- Gval partial + x update + stores (own halves) ----
        float gs = 0.f;
        f4_t xo;
        #pragma unroll
        for (int i = 0; i < 4; ++i) {
            float fb = fmaf(-BETA, xr[i], bmu[i]);
            gs = fmaf(fb, rr[i], gs);
            gs = fmaf(-0.5f * rr[i], ra[i], gs);
            float xn = fmaf(fb + ra[i], dt, xr[i]) + xg[i];
            xr[i] = xn;
            xo[i] = xn;
        }
        llr = fmaf(gs, dt, llr);
        ((f4_t*)(xs_out + (size_t)s * (BATCH * DX) + (size_t)brow * DX))[w * 4 + quad] = xo;
        ((f4_t*)(vs_out + (size_t)s * (BATCH * DX) + (size_t)brow * DX))[w * 4 + quad] = vA;

        // ---- roll state ----
        #pragma unroll
        for (int ml = 0; ml < 4; ++ml) {
            unsigned wa = w10p[2 * ml], wb = w10p[2 * ml + 1];
            cin[ml][0] = fmaf(dt, unplo(wa), cin[ml][0]);
            cin[ml][1] = fmaf(dt, unphi(wa), cin[ml][1]);
            cin[ml][2] = fmaf(dt, unplo(wb), cin[ml][2]);
            cin[ml][3] = fmaf(dt, unphi(wb), cin[ml][3]);
        }
        cw = nw;
        tcur = tnx;
    }

    // ---- ll: quad-reduce within wave, then cross-wave add via LDS ----
    llr += __shfl_xor(llr, 16, 64);
    llr += __shfl_xor(llr, 32, 64);
    if (lane < 16) sLL[w][lane] = llr;
    bar_lds();
    if (w == 0 && lane < 16) ll_out[r0 + lane] = sLL[0][lane] + sLL[1][lane];
}

extern "C" void kernel_launch(void* const* d_in, const int* in_sizes, int n_in,
                              void* d_out, int out_size, void* d_ws, size_t ws_size,
                              hipStream_t stream) {
    const float* x0 = (const float*)d_in[0];
    const float* ts = (const float*)d_in[1];
    const float* dWs = (const float*)d_in[2];
    const float* W1 = (const float*)d_in[3];
    const float* b1 = (const float*)d_in[4];
    const float* W2 = (const float*)d_in[5];
    const float* b2 = (const float*)d_in[6];
    const float* W3 = (const float*)d_in[7];
    const float* b3 = (const float*)d_in[8];
    const float* G  = (const float*)d_in[9];
    const float* mu = (const float*)d_in[10];
    const float* vt = (const float*)d_in[11];
    hipLaunchKernelGGL(sde_kernel, dim3(BATCH / 16), dim3(128), 0, stream,
                       x0, ts, dWs, W1, b1, W2, b2, W3, b3, G, mu, vt, (float*)d_out);
}

// Round 6
// 816.230 us; speedup vs baseline: 2.5378x; 1.0500x over previous
//
#include <hip/hip_runtime.h>
#include <math.h>

#define NSTEPS 500
#define BATCH  1024
#define DX     32
#define DW     32
#define HDIM   128
#define BETA   0.5f
#define EPSG   1e-4f
#define SC     2.8853900817779268f   // 2*log2(e): pre-scale for exp2-based sigmoid

typedef short bf8_t __attribute__((ext_vector_type(8)));
typedef float f4_t  __attribute__((ext_vector_type(4)));

union U8 { bf8_t v; unsigned u[4]; };

__device__ __forceinline__ f4_t MFMA(bf8_t a, bf8_t b, f4_t c) {
    return __builtin_amdgcn_mfma_f32_16x16x32_bf16(a, b, c, 0, 0, 0);
}

__device__ __forceinline__ unsigned short f2bf(float x) {   // RNE f32->bf16
    unsigned u = __float_as_uint(x);
    u += 0x7fffu + ((u >> 16) & 1u);
    return (unsigned short)(u >> 16);
}
__device__ __forceinline__ float bf2f(unsigned short h) {
    return __uint_as_float(((unsigned)h) << 16);
}
__device__ __forceinline__ unsigned cvtpk(float a, float b) {
    unsigned r;
    asm("v_cvt_pk_bf16_f32 %0, %1, %2" : "=v"(r) : "v"(a), "v"(b));
    return r;
}
__device__ __forceinline__ float unplo(unsigned u) { return __uint_as_float(u << 16); }
__device__ __forceinline__ float unphi(unsigned u) { return __uint_as_float(u & 0xffff0000u); }

__device__ __forceinline__ float exp2_hw(float x) {
    float r; asm("v_exp_f32 %0, %1" : "=v"(r) : "v"(x)); return r;
}
__device__ __forceinline__ float rcp_hw(float x) {
    float r; asm("v_rcp_f32 %0, %1" : "=v"(r) : "v"(x)); return r;
}
// sg = 1/(2^zs + 1); tanh(z) = 1 - 2*sg folded into next layer's weights/bias
__device__ __forceinline__ float sigm_s(float zs) {
    return rcp_hw(exp2_hw(zs) + 1.f);
}
__device__ __forceinline__ void hilo_pk(float a, float b, unsigned& hp, unsigned& lp) {
    hp = cvtpk(a, b);
    lp = cvtpk(a - unplo(hp), b - unphi(hp));
}
__device__ __forceinline__ void agpr_pin(bf8_t& v) { asm("" : "+a"(v)); }

// LDS barrier: orders LDS (lgkmcnt) but lets global loads/stores float across.
__device__ __forceinline__ void bar_lds() {
    __builtin_amdgcn_sched_barrier(0);
    asm volatile("s_waitcnt lgkmcnt(0)" ::: "memory");
    __builtin_amdgcn_s_barrier();
    __builtin_amdgcn_sched_barrier(0);
}

// ============================================================================
// 4-wave split, 3 barriers/step.  x-state REPLICATED on all waves (identical
// update -> no x/r exchange).  Wave w owns H-features [32w,32w+32) (2 m-tiles)
// for L1/L2.  Waves 0,1: v-tile w + u-packs.  Waves 2,3: ra-tile (w-2) + Gval.
// All waves: full xg (6 MFMA, duplicated) + full x-update from broadcast u/ra.
// Exchanges: {h1} bar1 {h2} bar2 {u-packs, ra} bar3.  Single-buffered: every
// read_s is lgkm-drained >=1 barrier before write_{s+1} (sRA written in P3).
// Weight A-fragments in AGPRs; k-slot sigma + k-tile rotation ktG[kf]=(w+kf)&3
// baked into fragments so all exchanges are same-lane LDS copies.
// ============================================================================
__global__ __launch_bounds__(256, 1)
void sde_kernel(const float* __restrict__ x0, const float* __restrict__ ts,
                const float* __restrict__ dWs,
                const float* __restrict__ W1, const float* __restrict__ b1,
                const float* __restrict__ W2, const float* __restrict__ b2,
                const float* __restrict__ W3, const float* __restrict__ b3,
                const float* __restrict__ G,  const float* __restrict__ mu,
                const float* __restrict__ vt, float* __restrict__ out)
{
    __shared__ float sts[NSTEPS + 1];
    __shared__ __align__(16) float sG[DX * DW];
    __shared__ __align__(16) unsigned sH1[4][64][4];
    __shared__ __align__(16) unsigned sB2[4][64][4];
    __shared__ __align__(16) unsigned sUH[2][64][2];
    __shared__ __align__(16) unsigned sUL[2][64][2];
    __shared__ __align__(16) f4_t sRA[2][64];
    __shared__ float sLL[2][16];

    const int tid  = threadIdx.x;
    const int w    = tid >> 6;       // wave id 0..3
    const int lane = tid & 63;
    const int m16  = lane & 15;      // batch column
    const int quad = lane >> 4;
    const int r0   = blockIdx.x * 16;
    const int brow = r0 + m16;

    for (int i = tid; i <= NSTEPS; i += 256) sts[i] = ts[i];
    for (int i = tid; i < DX * DW; i += 256) sG[i] = G[i];
    __syncthreads();

    // sigma k-slot map (group-local, 32-wide) and k-tile rotation
    int foS[8], ktG[4];
    #pragma unroll
    for (int j = 0; j < 8; ++j) foS[j] = (j < 4) ? (4 * quad + j) : (16 + 4 * quad + (j - 4));
    #pragma unroll
    for (int kf = 0; kf < 4; ++kf) ktG[kf] = (w + kf) & 3;

    // ---- L1/L2 weight fragments (own 2 m-tiles, features (2w+ml)*16+m16) ----
    bf8_t w1a[2];
    #pragma unroll
    for (int ml = 0; ml < 2; ++ml) {
        int mtg = 2 * w + ml;
        #pragma unroll
        for (int j = 0; j < 8; ++j)
            w1a[ml][j] = (short)f2bf(SC * W1[(1 + foS[j]) * HDIM + mtg * 16 + m16]);
        agpr_pin(w1a[ml]);
    }
    bf8_t w2a[2][4];
    #pragma unroll
    for (int ml = 0; ml < 2; ++ml) {
        int mtg = 2 * w + ml;
        #pragma unroll
        for (int kf = 0; kf < 4; ++kf) {
            #pragma unroll
            for (int j = 0; j < 8; ++j)
                w2a[ml][kf][j] = (short)f2bf(-2.f * SC * W2[(ktG[kf] * 32 + foS[j]) * HDIM + mtg * 16 + m16]);
            agpr_pin(w2a[ml][kf]);
        }
    }

    bf8_t ones;
    #pragma unroll
    for (int j = 0; j < 8; ++j) ones[j] = (short)0x3f80;

    // folded C-inits
    f4_t b2C[2];
    #pragma unroll
    for (int ml = 0; ml < 2; ++ml) {
        f4_t S = {0, 0, 0, 0};
        #pragma unroll
        for (int kf = 0; kf < 4; ++kf) S = MFMA(w2a[ml][kf], ones, S);
        #pragma unroll
        for (int i = 0; i < 4; ++i)
            b2C[ml][i] = fmaf(-0.5f, S[i], SC * b2[(2 * w + ml) * 16 + 4 * quad + i]);
    }

    // L1 t-bias state (own 2 m-tiles)
    f4_t cin[2];
    unsigned w10p[4];
    {
        float t0 = ts[0];
        #pragma unroll
        for (int ml = 0; ml < 2; ++ml) {
            int f0 = (2 * w + ml) * 16 + 4 * quad;
            float wa = SC * W1[f0],     wb = SC * W1[f0 + 1];
            float wc = SC * W1[f0 + 2], wd = SC * W1[f0 + 3];
            w10p[2 * ml]     = ((unsigned)f2bf(wb) << 16) | f2bf(wa);
            w10p[2 * ml + 1] = ((unsigned)f2bf(wd) << 16) | f2bf(wc);
            cin[ml][0] = fmaf(t0, wa, SC * b1[f0]);
            cin[ml][1] = fmaf(t0, wb, SC * b1[f0 + 1]);
            cin[ml][2] = fmaf(t0, wc, SC * b1[f0 + 2]);
            cin[ml][3] = fmaf(t0, wd, SC * b1[f0 + 3]);
        }
    }

    // full-dim constants (x replicated)
    f4_t bmu[2];
    float vtr[2][4];
    #pragma unroll
    for (int mt = 0; mt < 2; ++mt)
        #pragma unroll
        for (int i = 0; i < 4; ++i) {
            int f = mt * 16 + 4 * quad + i;
            bmu[mt][i] = BETA * mu[f];
            vtr[mt][i] = vt[f];
        }

    // G fragments (hi/lo), both m-tiles, all waves (for full xg)
    bf8_t ghi[2], glo[2];
    #pragma unroll
    for (int mt = 0; mt < 2; ++mt) {
        #pragma unroll
        for (int j = 0; j < 8; ++j) {
            float gv = sG[(mt * 16 + m16) * DW + foS[j]];
            unsigned short hg = f2bf(gv);
            ghi[mt][j] = (short)hg;
            glo[mt][j] = (short)f2bf(gv - bf2f(hg));
        }
        agpr_pin(ghi[mt]); agpr_pin(glo[mt]);
    }

    // waves 0,1: L3 weights + b3C + dW state.  waves 2,3: a = GG^T frags.
    bf8_t w3a[4], ahi, alo;
    f4_t b3C, cw;
    if (w < 2) {
        #pragma unroll
        for (int kf = 0; kf < 4; ++kf) {
            #pragma unroll
            for (int j = 0; j < 8; ++j)
                w3a[kf][j] = (short)f2bf(-2.f * W3[(ktG[kf] * 32 + foS[j]) * DW + w * 16 + m16]);
            agpr_pin(w3a[kf]);
        }
        f4_t S = {0, 0, 0, 0};
        #pragma unroll
        for (int kf = 0; kf < 4; ++kf) S = MFMA(w3a[kf], ones, S);
        #pragma unroll
        for (int i = 0; i < 4; ++i)
            b3C[i] = fmaf(-0.5f, S[i], b3[w * 16 + 4 * quad + i]);
        cw = ((const f4_t*)(dWs + (size_t)brow * DW))[w * 4 + quad];
    } else {
        int rowA = (w - 2) * 16 + m16;
        float gb[32];
        const f4_t* pb = (const f4_t*)(sG + rowA * DW);
        #pragma unroll
        for (int k4 = 0; k4 < 8; ++k4) {
            f4_t t = pb[k4];
            gb[4 * k4] = t[0]; gb[4 * k4 + 1] = t[1]; gb[4 * k4 + 2] = t[2]; gb[4 * k4 + 3] = t[3];
        }
        #pragma unroll
        for (int j = 0; j < 8; ++j) {
            const f4_t* pa = (const f4_t*)(sG + foS[j] * DW);
            float acc = 0.f;
            #pragma unroll
            for (int k4 = 0; k4 < 8; ++k4) {
                f4_t t = pa[k4];
                acc += t[0] * gb[4 * k4] + t[1] * gb[4 * k4 + 1]
                     + t[2] * gb[4 * k4 + 2] + t[3] * gb[4 * k4 + 3];
            }
            unsigned short h = f2bf(acc);
            ahi[j] = (short)h;
            alo[j] = (short)f2bf(acc - bf2f(h));
        }
        agpr_pin(ahi); agpr_pin(alo);
    }

    // ---- replicated x state (full 32 dims per lane-column) ----
    f4_t xr[2];
    {
        const f4_t* p = (const f4_t*)(x0 + (size_t)brow * DX);
        xr[0] = p[quad]; xr[1] = p[4 + quad];
    }

    const float T = sts[NSTEPS];
    float tcur = sts[0];
    float llr = 0.f;

    float* xs_out = out;
    float* vs_out = out + (size_t)NSTEPS * BATCH * DX;
    float* ll_out = out + (size_t)2 * NSTEPS * BATCH * DX;

    #pragma unroll 1
    for (int s = 0; s < NSTEPS; ++s) {
        const float tnx    = sts[s + 1];
        const float dt     = tnx - tcur;
        const float sqdt   = __builtin_amdgcn_sqrtf(dt);
        const float invrem = rcp_hw(T - tcur + EPSG);

        f4_t nw;
        if (w < 2) {
            int sn = (s + 1 < NSTEPS) ? s + 1 : s;
            nw = ((const f4_t*)(dWs + (size_t)sn * (BATCH * DW) + (size_t)brow * DW))[w * 4 + quad];
        }

        // ---- P1: L1 (own 2 m-tiles); waves 2,3 also r + ra ----
        U8 xb;
        xb.u[0] = cvtpk(xr[0][0], xr[0][1]); xb.u[1] = cvtpk(xr[0][2], xr[0][3]);
        xb.u[2] = cvtpk(xr[1][0], xr[1][1]); xb.u[3] = cvtpk(xr[1][2], xr[1][3]);
        U8 bhO;
        #pragma unroll
        for (int ml = 0; ml < 2; ++ml) {
            f4_t acc = MFMA(w1a[ml], xb.v, cin[ml]);
            bhO.u[2 * ml]     = cvtpk(sigm_s(acc[0]), sigm_s(acc[1]));
            bhO.u[2 * ml + 1] = cvtpk(sigm_s(acc[2]), sigm_s(acc[3]));
        }
        *(uint4*)&sH1[w][lane][0] = make_uint4(bhO.u[0], bhO.u[1], bhO.u[2], bhO.u[3]);

        float rr[2][4];
        f4_t raO;
        if (w >= 2) {
            #pragma unroll
            for (int mt = 0; mt < 2; ++mt)
                #pragma unroll
                for (int i = 0; i < 4; ++i) rr[mt][i] = (vtr[mt][i] - xr[mt][i]) * invrem;
            U8 rh, rl;
            hilo_pk(rr[0][0], rr[0][1], rh.u[0], rl.u[0]);
            hilo_pk(rr[0][2], rr[0][3], rh.u[1], rl.u[1]);
            hilo_pk(rr[1][0], rr[1][1], rh.u[2], rl.u[2]);
            hilo_pk(rr[1][2], rr[1][3], rh.u[3], rl.u[3]);
            raO = f4_t{0, 0, 0, 0};
            raO = MFMA(ahi, rh.v, raO);
            raO = MFMA(ahi, rl.v, raO);
            raO = MFMA(alo, rh.v, raO);
        }
        bar_lds();   // 1

        // ---- P2: L2 (own 2 m-tiles, K rotation own-first) ----
        uint4 h1 = *(const uint4*)&sH1[ktG[1]][lane][0];
        uint4 h2 = *(const uint4*)&sH1[ktG[2]][lane][0];
        uint4 h3 = *(const uint4*)&sH1[ktG[3]][lane][0];
        U8 f1, f2, f3;
        f1.u[0] = h1.x; f1.u[1] = h1.y; f1.u[2] = h1.z; f1.u[3] = h1.w;
        f2.u[0] = h2.x; f2.u[1] = h2.y; f2.u[2] = h2.z; f2.u[3] = h2.w;
        f3.u[0] = h3.x; f3.u[1] = h3.y; f3.u[2] = h3.z; f3.u[3] = h3.w;
        U8 b2O;
        #pragma unroll
        for (int ml = 0; ml < 2; ++ml) {
            f4_t acc = b2C[ml];
            acc = MFMA(w2a[ml][0], bhO.v, acc);
            acc = MFMA(w2a[ml][1], f1.v, acc);
            acc = MFMA(w2a[ml][2], f2.v, acc);
            acc = MFMA(w2a[ml][3], f3.v, acc);
            b2O.u[2 * ml]     = cvtpk(sigm_s(acc[0]), sigm_s(acc[1]));
            b2O.u[2 * ml + 1] = cvtpk(sigm_s(acc[2]), sigm_s(acc[3]));
        }
        *(uint4*)&sB2[w][lane][0] = make_uint4(b2O.u[0], b2O.u[1], b2O.u[2], b2O.u[3]);
        bar_lds();   // 2

        // ---- P3: waves 0,1: L3 -> v, u-packs.  waves 2,3: ra write + Gval ----
        f4_t vA;
        if (w < 2) {
            uint4 p1 = *(const uint4*)&sB2[ktG[1]][lane][0];
            uint4 p2 = *(const uint4*)&sB2[ktG[2]][lane][0];
            uint4 p3 = *(const uint4*)&sB2[ktG[3]][lane][0];
            U8 g1, g2, g3;
            g1.u[0] = p1.x; g1.u[1] = p1.y; g1.u[2] = p1.z; g1.u[3] = p1.w;
            g2.u[0] = p2.x; g2.u[1] = p2.y; g2.u[2] = p2.z; g2.u[3] = p2.w;
            g3.u[0] = p3.x; g3.u[1] = p3.y; g3.u[2] = p3.z; g3.u[3] = p3.w;
            vA = b3C;
            vA = MFMA(w3a[0], b2O.v, vA);
            vA = MFMA(w3a[1], g1.v, vA);
            vA = MFMA(w3a[2], g2.v, vA);
            vA = MFMA(w3a[3], g3.v, vA);
            float u0 = fmaf(vA[0], dt, cw[0] * sqdt);
            float u1 = fmaf(vA[1], dt, cw[1] * sqdt);
            float u2 = fmaf(vA[2], dt, cw[2] * sqdt);
            float u3 = fmaf(vA[3], dt, cw[3] * sqdt);
            unsigned uh0, uh1, ul0, ul1;
            hilo_pk(u0, u1, uh0, ul0);
            hilo_pk(u2, u3, uh1, ul1);
            *(uint2*)&sUH[w][lane][0] = make_uint2(uh0, uh1);
            *(uint2*)&sUL[w][lane][0] = make_uint2(ul0, ul1);
        } else {
            sRA[w - 2][lane] = raO;
            int tw = w - 2;
            float gs = 0.f;
            #pragma unroll
            for (int i = 0; i < 4; ++i) {
                float fb = fmaf(-BETA, xr[tw][i], bmu[tw][i]);
                gs = fmaf(fb, rr[tw][i], gs);
                gs = fmaf(-0.5f * rr[tw][i], raO[i], gs);
            }
            llr = fmaf(gs, dt, llr);
        }
        bar_lds();   // 3

        // ---- P4: all waves: full xg + full x-update (identical) ----
        uint2 ua = *(const uint2*)&sUH[0][lane][0];
        uint2 ub = *(const uint2*)&sUH[1][lane][0];
        uint2 la = *(const uint2*)&sUL[0][lane][0];
        uint2 lb = *(const uint2*)&sUL[1][lane][0];
        U8 uhF, ulF;
        uhF.u[0] = ua.x; uhF.u[1] = ua.y; uhF.u[2] = ub.x; uhF.u[3] = ub.y;
        ulF.u[0] = la.x; ulF.u[1] = la.y; ulF.u[2] = lb.x; ulF.u[3] = lb.y;
        f4_t raF0 = sRA[0][lane];
        f4_t raF1 = sRA[1][lane];
        f4_t xg0 = {0, 0, 0, 0}, xg1 = {0, 0, 0, 0};
        xg0 = MFMA(ghi[0], uhF.v, xg0);
        xg0 = MFMA(ghi[0], ulF.v, xg0);
        xg0 = MFMA(glo[0], uhF.v, xg0);
        xg1 = MFMA(ghi[1], uhF.v, xg1);
        xg1 = MFMA(ghi[1], ulF.v, xg1);
        xg1 = MFMA(glo[1], uhF.v, xg1);
        f4_t xo0, xo1;
        #pragma unroll
        for (int i = 0; i < 4; ++i) {
            float fb0 = fmaf(-BETA, xr[0][i], bmu[0][i]);
            float fb1 = fmaf(-BETA, xr[1][i], bmu[1][i]);
            xo0[i] = fmaf(fb0 + raF0[i], dt, xr[0][i]) + xg0[i];
            xo1[i] = fmaf(fb1 + raF1[i], dt, xr[1][i]) + xg1[i];
        }
        xr[0] = xo0; xr[1] = xo1;
        if (w < 2) {
            ((f4_t*)(xs_out + (size_t)s * (BATCH * DX) + (size_t)brow * DX))[w * 4 + quad] = (w == 0) ? xo0 : xo1;
            ((f4_t*)(vs_out + (size_t)s * (BATCH * DX) + (size_t)brow * DX))[w * 4 + quad] = vA;
            cw = nw;
        }

        // roll cin + time
        #pragma unroll
        for (int ml = 0; ml < 2; ++ml) {
            unsigned wa = w10p[2 * ml], wb = w10p[2 * ml + 1];
            cin[ml][0] = fmaf(dt, unplo(wa), cin[ml][0]);
            cin[ml][1] = fmaf(dt, unphi(wa), cin[ml][1]);
            cin[ml][2] = fmaf(dt, unplo(wb), cin[ml][2]);
            cin[ml][3] = fmaf(dt, unphi(wb), cin[ml][3]);
        }
        tcur = tnx;
    }

    // ---- ll: waves 2,3 hold tile partials; reduce + combine ----
    if (w >= 2) {
        llr += __shfl_xor(llr, 16, 64);
        llr += __shfl_xor(llr, 32, 64);
        if (lane < 16) sLL[w - 2][lane] = llr;
    }
    bar_lds();
    if (w == 0 && lane < 16) ll_out[r0 + lane] = sLL[0][lane] + sLL[1][lane];
}

extern "C" void kernel_launch(void* const* d_in, const int* in_sizes, int n_in,
                              void* d_out, int out_size, void* d_ws, size_t ws_size,
                              hipStream_t stream) {
    const float* x0 = (const float*)d_in[0];
    const float* ts = (const float*)d_in[1];
    const float* dWs = (const float*)d_in[2];
    const float* W1 = (const float*)d_in[3];
    const float* b1 = (const float*)d_in[4];
    const float* W2 = (const float*)d_in[5];
    const float* b2 = (const float*)d_in[6];
    const float* W3 = (const float*)d_in[7];
    const float* b3 = (const float*)d_in[8];
    const float* G  = (const float*)d_in[9];
    const float* mu = (const float*)d_in[10];
    const float* vt = (const float*)d_in[11];
    hipLaunchKernelGGL(sde_kernel, dim3(BATCH / 16), dim3(256), 0, stream,
                       x0, ts, dWs, W1, b1, W2, b2, W3, b3, G, mu, vt, (float*)d_out);
}